// Round 1
// baseline (1584.109 us; speedup 1.0000x reference)
//
#include <hip/hip_runtime.h>
#include <stdint.h>

#define NM 10000
#define NG 100000
#define NE 300000
#define DD 256
#define HH 256
#define AGP 260   // aggL row pitch in f32 (+4 pad -> 4-bank shift per row)

typedef unsigned short u16;
typedef float f32x4 __attribute__((ext_vector_type(4)));
typedef short bf16x8 __attribute__((ext_vector_type(8)));

__device__ __forceinline__ u16 f2bf(float f) {
    union { float f; unsigned int i; } v; v.f = f;
    unsigned int x = v.i;
    x += 0x7fffu + ((x >> 16) & 1u);   // RNE
    return (u16)(x >> 16);
}
__device__ __forceinline__ unsigned int pack2(u16 lo, u16 hi) {
    return (unsigned int)lo | ((unsigned int)hi << 16);
}
__device__ __forceinline__ uint4 pack8(float4 v0, float4 v1) {
    uint4 o;
    o.x = pack2(f2bf(v0.x), f2bf(v0.y));
    o.y = pack2(f2bf(v0.z), f2bf(v0.w));
    o.z = pack2(f2bf(v1.x), f2bf(v1.y));
    o.w = pack2(f2bf(v1.z), f2bf(v1.w));
    return o;
}

// ------- weight transpose + downcast: in f32[K][N] -> out bf16[N][K] -------
__global__ void transpose_f32_to_bf16T(const float* __restrict__ in,
                                       u16* __restrict__ out, int K, int N) {
    __shared__ float tile[64][68];        // +4 pad, rows 16B aligned
    const int ntn = N >> 6;
    const int tk = blockIdx.x / ntn;
    const int tn = blockIdx.x % ntn;
    const int k0 = tk << 6, n0 = tn << 6;
    const int tid = threadIdx.x;
    #pragma unroll
    for (int i = 0; i < 4; ++i) {
        int flat = tid + 256 * i;         // 1024 float4 chunks
        int r = flat >> 4;
        int c = (flat & 15) << 2;
        *(float4*)&tile[r][c] = *(const float4*)(in + (size_t)(k0 + r) * N + n0 + c);
    }
    __syncthreads();
    #pragma unroll
    for (int i = 0; i < 2; ++i) {
        int flat = tid + 256 * i;
        int r = flat >> 3;                // output row (n)
        int c = (flat & 7) << 3;          // output col (k), 8 per thread
        uint4 o;
        o.x = pack2(f2bf(tile[c + 0][r]), f2bf(tile[c + 1][r]));
        o.y = pack2(f2bf(tile[c + 2][r]), f2bf(tile[c + 3][r]));
        o.z = pack2(f2bf(tile[c + 4][r]), f2bf(tile[c + 5][r]));
        o.w = pack2(f2bf(tile[c + 6][r]), f2bf(tile[c + 7][r]));
        *(uint4*)(out + (size_t)(n0 + r) * K + k0 + c) = o;
    }
}

// ---------------- CSR build: histogram -> scan -> scatter ----------------
__global__ void hist_k(const int* __restrict__ edst, int* __restrict__ cnt) {
    int i = blockIdx.x * blockDim.x + threadIdx.x;
    const int stride = gridDim.x * blockDim.x;
    for (; i < NE; i += stride) atomicAdd(&cnt[edst[i]], 1);
}

// one block, 1024 threads; cnt may alias cursor (in-place read-then-write).
__global__ void scan_k(const int* cnt, int* row_start, int* cursor) {
    __shared__ int part[1024];
    const int t = threadIdx.x;
    const int chunk = (NG + 1023) / 1024;       // 98
    const int lo = t * chunk;
    const int hi = (lo + chunk < NG) ? lo + chunk : NG;
    int s = 0;
    for (int i = lo; i < hi; ++i) s += cnt[i];
    part[t] = s;
    __syncthreads();
    if (t == 0) {
        int run = 0;
        for (int i = 0; i < 1024; ++i) { int v = part[i]; part[i] = run; run += v; }
    }
    __syncthreads();
    int run = part[t];
    for (int i = lo; i < hi; ++i) {
        int v = cnt[i];
        row_start[i] = run;
        cursor[i] = run;
        run += v;
    }
    if (t == 0) row_start[NG] = NE;
}

__global__ void scatter_k(const int* __restrict__ edst, int* cursor,
                          int* __restrict__ eid) {
    int i = blockIdx.x * blockDim.x + threadIdx.x;
    const int stride = gridDim.x * blockDim.x;
    for (; i < NE; i += stride) {
        int pos = atomicAdd(&cursor[edst[i]], 1);
        eid[pos] = i;
    }
}

// ---------------- edge MLP + owned-row aggregation ----------------
// Block owns grid rows [r0, r0+64). Its incoming edges are eid[beg:end]
// (contiguous, CSR-sorted by dst). Edge MLP runs in tiles of 64 edges;
// GEMM2 output accumulates into LDS aggL[64][AGP] f32 via LDS atomics;
// each agg row is then written ONCE with plain stores. Zero global atomics.
__global__ __launch_bounds__(256, 1) void edge_agg(
    const float* __restrict__ mesh_x, const float* __restrict__ grid_x,
    const int* __restrict__ esrc, const int* __restrict__ edst,
    const int* __restrict__ row_start, const int* __restrict__ eid,
    const u16* __restrict__ w1T, const float* __restrict__ b1,
    const u16* __restrict__ w2T, const float* __restrict__ b2,
    float* __restrict__ agg)
{
    extern __shared__ char smem[];
    float* aggL = (float*)smem;                        // [64][AGP] f32  (66560 B)
    u16* aC = (u16*)(smem + 64 * AGP * 4);             // [64][32]       (4096 B)
    u16* bC = aC + 64 * 32;                            // [256][32]      (16384 B)
    u16* hL = bC + 256 * 32;                           // [64][272]      (34816 B)
    int* ssrc = (int*)(hL + 64 * 272);                 // [64]
    int* sdst = ssrc + 64;                             // [64]

    const int tid = threadIdx.x;
    const int r0 = blockIdx.x * 64;
    const int rEnd = (r0 + 64 < NG) ? r0 + 64 : NG;
    const int beg = row_start[r0];
    const int end = row_start[rEnd];

    const int wv = tid >> 6;
    const int lane = tid & 63;
    const int m = lane & 15;
    const int q = lane >> 4;
    const int sr = tid >> 2;              // staging row 0..63 (edge in tile)
    const int sc8 = (tid & 3) * 8;        // staging col (8 f32 per lane)

    for (int i = tid; i < 64 * AGP; i += 256) aggL[i] = 0.f;

    f32x4 zero = {0.f, 0.f, 0.f, 0.f};

    for (int t0 = beg; t0 < end; t0 += 64) {
        const int nT = (end - t0 < 64) ? end - t0 : 64;
        __syncthreads();                  // aggL zeroed / prior tile consumed
        if (tid < 64) {
            int e = eid[t0 + ((tid < nT) ? tid : 0)];   // pad tail w/ dup edge
            ssrc[tid] = esrc[e];
            sdst[tid] = edst[e];
        }
        f32x4 acc[4][4];
        #pragma unroll
        for (int i = 0; i < 4; ++i)
            #pragma unroll
            for (int j = 0; j < 4; ++j) acc[i][j] = zero;
        __syncthreads();                  // indices visible

        // ---- GEMM1: K = 512 (concat mesh_x[src] | grid_x[dst]) ----
        for (int kt = 0; kt < 16; ++kt) {
            const int kg = kt * 32;
            if (kt) __syncthreads();
            {
                const int col = kg + sc8;
                const float* p = (col < DD)
                    ? (mesh_x + (size_t)ssrc[sr] * DD + col)
                    : (grid_x + (size_t)sdst[sr] * DD + (col - DD));
                float4 v0 = *(const float4*)p;
                float4 v1 = *(const float4*)(p + 4);
                *(uint4*)&aC[sr * 32 + sc8] = pack8(v0, v1);
            }
            #pragma unroll
            for (int i = 0; i < 4; ++i) {
                int flat = tid + 256 * i;
                int n = flat >> 2;
                int c = (flat & 3) * 8;
                *(uint4*)&bC[n * 32 + c] = *(const uint4*)(w1T + (size_t)n * 512 + kg + c);
            }
            __syncthreads();
            bf16x8 af[4], bfr[4];
            #pragma unroll
            for (int et = 0; et < 4; ++et)
                af[et] = *(const bf16x8*)&aC[(et * 16 + m) * 32 + q * 8];
            #pragma unroll
            for (int ht = 0; ht < 4; ++ht)
                bfr[ht] = *(const bf16x8*)&bC[(wv * 64 + ht * 16 + m) * 32 + q * 8];
            #pragma unroll
            for (int ht = 0; ht < 4; ++ht)
                #pragma unroll
                for (int et = 0; et < 4; ++et)
                    acc[ht][et] = __builtin_amdgcn_mfma_f32_16x16x32_bf16(
                        bfr[ht], af[et], acc[ht][et], 0, 0, 0);
        }

        // ---- epilogue 1: bias + relu -> hL[edge][hidden] bf16 ----
        #pragma unroll
        for (int ht = 0; ht < 4; ++ht) {
            const int hb = wv * 64 + ht * 16 + q * 4;
            const float4 bb = *(const float4*)(b1 + hb);
            #pragma unroll
            for (int et = 0; et < 4; ++et) {
                const int e = et * 16 + m;
                ushort4 o;
                o.x = f2bf(fmaxf(acc[ht][et][0] + bb.x, 0.f));
                o.y = f2bf(fmaxf(acc[ht][et][1] + bb.y, 0.f));
                o.z = f2bf(fmaxf(acc[ht][et][2] + bb.z, 0.f));
                o.w = f2bf(fmaxf(acc[ht][et][3] + bb.w, 0.f));
                *(ushort4*)&hL[e * 272 + hb] = o;
            }
        }
        #pragma unroll
        for (int i = 0; i < 4; ++i)
            #pragma unroll
            for (int j = 0; j < 4; ++j) acc[i][j] = zero;
        __syncthreads();                  // hL visible to all waves

        // ---- GEMM2: K = 256 ----
        for (int kt = 0; kt < 8; ++kt) {
            const int kg = kt * 32;
            if (kt) __syncthreads();
            #pragma unroll
            for (int i = 0; i < 4; ++i) {
                int flat = tid + 256 * i;
                int n = flat >> 2;
                int c = (flat & 3) * 8;
                *(uint4*)&bC[n * 32 + c] = *(const uint4*)(w2T + (size_t)n * 256 + kg + c);
            }
            __syncthreads();
            bf16x8 af[4], bfr[4];
            #pragma unroll
            for (int et = 0; et < 4; ++et)
                af[et] = *(const bf16x8*)&hL[(et * 16 + m) * 272 + kg + q * 8];
            #pragma unroll
            for (int ht = 0; ht < 4; ++ht)
                bfr[ht] = *(const bf16x8*)&bC[(wv * 64 + ht * 16 + m) * 32 + q * 8];
            #pragma unroll
            for (int ht = 0; ht < 4; ++ht)
                #pragma unroll
                for (int et = 0; et < 4; ++et)
                    acc[ht][et] = __builtin_amdgcn_mfma_f32_16x16x32_bf16(
                        bfr[ht], af[et], acc[ht][et], 0, 0, 0);
        }

        // ---- epilogue 2: accumulate (acc + b2) into aggL via LDS atomics ----
        #pragma unroll
        for (int nt = 0; nt < 4; ++nt) {
            const int nb = wv * 64 + nt * 16 + q * 4;
            const float4 bb = *(const float4*)(b2 + nb);
            #pragma unroll
            for (int et = 0; et < 4; ++et) {
                const int el = et * 16 + m;
                if (el < nT) {
                    const int dL = sdst[el] - r0;      // in [0,64)
                    float* p = &aggL[dL * AGP + nb];
                    atomicAdd(p + 0, acc[nt][et][0] + bb.x);
                    atomicAdd(p + 1, acc[nt][et][1] + bb.y);
                    atomicAdd(p + 2, acc[nt][et][2] + bb.z);
                    atomicAdd(p + 3, acc[nt][et][3] + bb.w);
                }
            }
        }
    }

    __syncthreads();                      // all LDS adds done
    // ---- write each agg row once (plain coalesced stores) ----
    const int rr = tid >> 2;              // 0..63
    const int c0 = (tid & 3) * 64;
    if (r0 + rr < NG) {
        float* dst = agg + (size_t)(r0 + rr) * HH + c0;
        const float* srcp = &aggL[rr * AGP + c0];
        #pragma unroll
        for (int i = 0; i < 16; ++i)
            *(float4*)(dst + i * 4) = *(const float4*)(srcp + i * 4);
    }
}

// ---------------- grid MLP + residual (unchanged) ----------------
// agg is f32 [NG][HH] living in d_out; each block reads only the rows it
// later overwrites with the final f32 output (block-local read-then-write).
// NOTE: agg and out alias — no __restrict__ on them.
__global__ __launch_bounds__(256, 2) void grid_mlp(
    const float* __restrict__ grid_x, const float* agg,
    const u16* __restrict__ w1T, const float* __restrict__ b1,
    const u16* __restrict__ w2T, const float* __restrict__ b2,
    float* out)
{
    __shared__ u16 aC[64 * 32];
    __shared__ u16 bC[256 * 32];
    __shared__ u16 hL[64 * 272];

    const int tid = threadIdx.x;
    const int r0 = blockIdx.x * 64;
    const int wv = tid >> 6;
    const int lane = tid & 63;
    const int m = lane & 15;
    const int q = lane >> 4;
    const int sr = tid >> 2;
    const int sc8 = (tid & 3) * 8;
    int srow = r0 + sr; if (srow >= NG) srow = NG - 1;  // clamp stays inside this block's rows

    f32x4 zero = {0.f, 0.f, 0.f, 0.f};
    f32x4 acc[4][4];
    #pragma unroll
    for (int i = 0; i < 4; ++i)
        #pragma unroll
        for (int j = 0; j < 4; ++j) acc[i][j] = zero;

    // ---- GEMM1: K = 512 (concat grid_x | agg), f32 -> bf16 stage
    for (int kt = 0; kt < 16; ++kt) {
        const int kg = kt * 32;
        if (kt) __syncthreads();
        {
            const int col = kg + sc8;
            const float* p = (col < DD)
                ? (grid_x + (size_t)srow * DD + col)
                : (agg + (size_t)srow * HH + (col - DD));
            float4 v0 = *(const float4*)p;
            float4 v1 = *(const float4*)(p + 4);
            *(uint4*)&aC[sr * 32 + sc8] = pack8(v0, v1);
        }
        #pragma unroll
        for (int i = 0; i < 4; ++i) {
            int flat = tid + 256 * i;
            int n = flat >> 2;
            int c = (flat & 3) * 8;
            *(uint4*)&bC[n * 32 + c] = *(const uint4*)(w1T + (size_t)n * 512 + kg + c);
        }
        __syncthreads();
        bf16x8 af[4], bfr[4];
        #pragma unroll
        for (int et = 0; et < 4; ++et)
            af[et] = *(const bf16x8*)&aC[(et * 16 + m) * 32 + q * 8];
        #pragma unroll
        for (int ht = 0; ht < 4; ++ht)
            bfr[ht] = *(const bf16x8*)&bC[(wv * 64 + ht * 16 + m) * 32 + q * 8];
        #pragma unroll
        for (int ht = 0; ht < 4; ++ht)
            #pragma unroll
            for (int et = 0; et < 4; ++et)
                acc[ht][et] = __builtin_amdgcn_mfma_f32_16x16x32_bf16(
                    bfr[ht], af[et], acc[ht][et], 0, 0, 0);
    }

    #pragma unroll
    for (int ht = 0; ht < 4; ++ht) {
        const int hb = wv * 64 + ht * 16 + q * 4;
        const float4 bb = *(const float4*)(b1 + hb);
        #pragma unroll
        for (int et = 0; et < 4; ++et) {
            const int e = et * 16 + m;
            ushort4 o;
            o.x = f2bf(fmaxf(acc[ht][et][0] + bb.x, 0.f));
            o.y = f2bf(fmaxf(acc[ht][et][1] + bb.y, 0.f));
            o.z = f2bf(fmaxf(acc[ht][et][2] + bb.z, 0.f));
            o.w = f2bf(fmaxf(acc[ht][et][3] + bb.w, 0.f));
            *(ushort4*)&hL[e * 272 + hb] = o;
        }
    }
    #pragma unroll
    for (int i = 0; i < 4; ++i)
        #pragma unroll
        for (int j = 0; j < 4; ++j) acc[i][j] = zero;
    __syncthreads();

    // ---- GEMM2: K = 256
    for (int kt = 0; kt < 8; ++kt) {
        const int kg = kt * 32;
        if (kt) __syncthreads();
        #pragma unroll
        for (int i = 0; i < 4; ++i) {
            int flat = tid + 256 * i;
            int n = flat >> 2;
            int c = (flat & 3) * 8;
            *(uint4*)&bC[n * 32 + c] = *(const uint4*)(w2T + (size_t)n * 256 + kg + c);
        }
        __syncthreads();
        bf16x8 af[4], bfr[4];
        #pragma unroll
        for (int et = 0; et < 4; ++et)
            af[et] = *(const bf16x8*)&hL[(et * 16 + m) * 272 + kg + q * 8];
        #pragma unroll
        for (int ht = 0; ht < 4; ++ht)
            bfr[ht] = *(const bf16x8*)&bC[(wv * 64 + ht * 16 + m) * 32 + q * 8];
        #pragma unroll
        for (int ht = 0; ht < 4; ++ht)
            #pragma unroll
            for (int et = 0; et < 4; ++et)
                acc[ht][et] = __builtin_amdgcn_mfma_f32_16x16x32_bf16(
                    bfr[ht], af[et], acc[ht][et], 0, 0, 0);
    }

    // ---- epilogue: + b2 + residual grid_x, store f32 (overwrites agg rows)
    #pragma unroll
    for (int nt = 0; nt < 4; ++nt) {
        const int nb = wv * 64 + nt * 16 + q * 4;
        const float4 bb = *(const float4*)(b2 + nb);
        #pragma unroll
        for (int et = 0; et < 4; ++et) {
            const int r = r0 + et * 16 + m;
            if (r < NG) {
                const float4 g = *(const float4*)(grid_x + (size_t)r * DD + nb);
                float4 o;
                o.x = acc[nt][et][0] + bb.x + g.x;
                o.y = acc[nt][et][1] + bb.y + g.y;
                o.z = acc[nt][et][2] + bb.z + g.z;
                o.w = acc[nt][et][3] + bb.w + g.w;
                *(float4*)(out + (size_t)r * DD + nb) = o;
            }
        }
    }
}

extern "C" void kernel_launch(void* const* d_in, const int* in_sizes, int n_in,
                              void* d_out, int out_size, void* d_ws, size_t ws_size,
                              hipStream_t stream)
{
    const float* mesh_x = (const float*)d_in[0];
    const float* grid_x = (const float*)d_in[1];
    const int* esrc     = (const int*)d_in[2];
    const int* edst     = (const int*)d_in[3];
    const float* w1e    = (const float*)d_in[4];
    const float* b1e    = (const float*)d_in[5];
    const float* w2e    = (const float*)d_in[6];
    const float* b2e    = (const float*)d_in[7];
    const float* w1g    = (const float*)d_in[8];
    const float* b1g    = (const float*)d_in[9];
    const float* w2g    = (const float*)d_in[10];
    const float* b2g    = (const float*)d_in[11];
    float* out = (float*)d_out;

    // d_ws layout: 4 transposed bf16 weights (768 KB) + CSR (2.0 MB)
    u16* w1eT = (u16*)d_ws;
    u16* w2eT = w1eT + 512 * 256;
    u16* w1gT = w2eT + 256 * 256;
    u16* w2gT = w1gT + 512 * 256;
    int* row_start = (int*)(w2gT + 256 * 256);   // [NG+1] (+1 pad for alignment)
    int* cursor    = row_start + NG + 2;         // [NG]
    int* eid       = cursor + NG;                // [NE]

    hipMemsetAsync(cursor, 0, (size_t)NG * sizeof(int), stream);

    transpose_f32_to_bf16T<<<32, 256, 0, stream>>>(w1e, w1eT, 512, 256);
    transpose_f32_to_bf16T<<<16, 256, 0, stream>>>(w2e, w2eT, 256, 256);
    transpose_f32_to_bf16T<<<32, 256, 0, stream>>>(w1g, w1gT, 512, 256);
    transpose_f32_to_bf16T<<<16, 256, 0, stream>>>(w2g, w2gT, 256, 256);

    // CSR build: hist -> scan -> scatter
    hist_k<<<256, 256, 0, stream>>>(edst, cursor);
    scan_k<<<1, 1024, 0, stream>>>(cursor, row_start, cursor);
    scatter_k<<<256, 256, 0, stream>>>(edst, cursor, eid);

    // edge MLP + owned-row aggregation (zero global atomics)
    const int smem_bytes = 64 * AGP * 4 + 64 * 32 * 2 + 256 * 32 * 2
                         + 64 * 272 * 2 + 128 * 4;   // 122368 B
    hipFuncSetAttribute(reinterpret_cast<const void*>(edge_agg),
                        hipFuncAttributeMaxDynamicSharedMemorySize, smem_bytes);
    edge_agg<<<(NG + 63) / 64, 256, smem_bytes, stream>>>(
        mesh_x, grid_x, esrc, edst, row_start, eid,
        w1eT, b1e, w2eT, b2e, (float*)d_out);

    grid_mlp<<<(NG + 63) / 64, 256, 0, stream>>>(
        grid_x, (const float*)d_out, w1gT, b1g, w2gT, b2g, out);
}

// Round 2
// 920.793 us; speedup vs baseline: 1.7204x; 1.7204x over previous
//
#include <hip/hip_runtime.h>
#include <stdint.h>

#define NM 10000
#define NG 100000
#define NE 300000
#define DD 256
#define HH 256

typedef unsigned short u16;
typedef float f32x4 __attribute__((ext_vector_type(4)));
typedef short bf16x8 __attribute__((ext_vector_type(8)));

__device__ __forceinline__ u16 f2bf(float f) {
    union { float f; unsigned int i; } v; v.f = f;
    unsigned int x = v.i;
    x += 0x7fffu + ((x >> 16) & 1u);   // RNE
    return (u16)(x >> 16);
}
__device__ __forceinline__ unsigned int pack2(u16 lo, u16 hi) {
    return (unsigned int)lo | ((unsigned int)hi << 16);
}
__device__ __forceinline__ uint4 pack8(float4 v0, float4 v1) {
    uint4 o;
    o.x = pack2(f2bf(v0.x), f2bf(v0.y));
    o.y = pack2(f2bf(v0.z), f2bf(v0.w));
    o.z = pack2(f2bf(v1.x), f2bf(v1.y));
    o.w = pack2(f2bf(v1.z), f2bf(v1.w));
    return o;
}

// ------- weight transpose + downcast: in f32[K][N] -> out bf16[N][K] -------
__global__ void transpose_f32_to_bf16T(const float* __restrict__ in,
                                       u16* __restrict__ out, int K, int N) {
    __shared__ float tile[64][68];        // +4 pad, rows 16B aligned
    const int ntn = N >> 6;
    const int tk = blockIdx.x / ntn;
    const int tn = blockIdx.x % ntn;
    const int k0 = tk << 6, n0 = tn << 6;
    const int tid = threadIdx.x;
    #pragma unroll
    for (int i = 0; i < 4; ++i) {
        int flat = tid + 256 * i;         // 1024 float4 chunks
        int r = flat >> 4;
        int c = (flat & 15) << 2;
        *(float4*)&tile[r][c] = *(const float4*)(in + (size_t)(k0 + r) * N + n0 + c);
    }
    __syncthreads();
    #pragma unroll
    for (int i = 0; i < 2; ++i) {
        int flat = tid + 256 * i;
        int r = flat >> 3;                // output row (n)
        int c = (flat & 7) << 3;          // output col (k), 8 per thread
        uint4 o;
        o.x = pack2(f2bf(tile[c + 0][r]), f2bf(tile[c + 1][r]));
        o.y = pack2(f2bf(tile[c + 2][r]), f2bf(tile[c + 3][r]));
        o.z = pack2(f2bf(tile[c + 4][r]), f2bf(tile[c + 5][r]));
        o.w = pack2(f2bf(tile[c + 6][r]), f2bf(tile[c + 7][r]));
        *(uint4*)(out + (size_t)(n0 + r) * K + k0 + c) = o;
    }
}

// ---------------- CSR build: histogram -> scan -> scatter ----------------
__global__ void hist_k(const int* __restrict__ edst, int* __restrict__ cnt) {
    int i = blockIdx.x * blockDim.x + threadIdx.x;
    const int stride = gridDim.x * blockDim.x;
    for (; i < NE; i += stride) atomicAdd(&cnt[edst[i]], 1);
}

// one block, 1024 threads; cnt may alias cursor (in-place read-then-write).
__global__ void scan_k(const int* cnt, int* row_start, int* cursor) {
    __shared__ int part[1024];
    const int t = threadIdx.x;
    const int chunk = (NG + 1023) / 1024;       // 98
    const int lo = t * chunk;
    const int hi = (lo + chunk < NG) ? lo + chunk : NG;
    int s = 0;
    for (int i = lo; i < hi; ++i) s += cnt[i];
    const int own = s;
    part[t] = s;
    __syncthreads();
    // parallel inclusive scan (doubling), then convert to exclusive
    for (int off = 1; off < 1024; off <<= 1) {
        int v = (t >= off) ? part[t - off] : 0;
        __syncthreads();
        part[t] += v;
        __syncthreads();
    }
    int run = part[t] - own;                    // exclusive prefix
    for (int i = lo; i < hi; ++i) {
        int v = cnt[i];
        row_start[i] = run;
        cursor[i] = run;
        run += v;
    }
    if (t == 0) row_start[NG] = NE;
}

__global__ void scatter_k(const int* __restrict__ edst, int* cursor,
                          int* __restrict__ eid) {
    int i = blockIdx.x * blockDim.x + threadIdx.x;
    const int stride = gridDim.x * blockDim.x;
    for (; i < NE; i += stride) {
        int pos = atomicAdd(&cursor[edst[i]], 1);
        eid[pos] = i;
    }
}

// ---------------- edge MLP + GEMM3 segment-sum aggregation ----------------
// One block per 64 CSR-consecutive edges (sorted by dst). GEMM1/GEMM2 as
// before. Aggregation: agg_part[h][r] = sum_el h2[el][h] * S[el][r], with S
// a one-hot bf16 rank-selection matrix (rank = index of distinct dst run).
// h2 fed twice as exact bf16 hi/lo split -> f32-exact segment sums.
// Interior ranks are exclusively owned (CSR) -> plain float4 stores;
// ranks 0 and nD-1 may straddle blocks -> unsafeAtomicAdd (~2 rows/block).
__global__ __launch_bounds__(256, 2) void edge_mlp_csr(
    const float* __restrict__ mesh_x, const float* __restrict__ grid_x,
    const int* __restrict__ esrc, const int* __restrict__ edst,
    const int* __restrict__ eid,
    const u16* __restrict__ w1T, const float* __restrict__ b1,
    const u16* __restrict__ w2T, const float* __restrict__ b2,
    float* __restrict__ agg)
{
    extern __shared__ char smem[];
    u16* aC = (u16*)smem;                 // [64][32]                  4096 B
    u16* bC = aC + 64 * 32;               // [256][32]                16384 B
    u16* hL = bC + 256 * 32;              // h1 [64][272] / h2 [256][68] 34816 B
    u16* sL = hL + 64 * 272;              // S  [64][68]               8704 B
    int* ssrc = (int*)(sL + 64 * 68);     // [64]
    int* sdst = ssrc + 64;                // [64]
    int* rowOfRank = sdst + 64;           // [64]
    int* misc = rowOfRank + 64;           // [0] = nD

    const int tid = threadIdx.x;
    const int e0 = blockIdx.x * 64;
    const int nT = (NE - e0 < 64) ? (NE - e0) : 64;

    const int wv = tid >> 6;
    const int lane = tid & 63;
    const int m = lane & 15;
    const int q = lane >> 4;
    const int sr = tid >> 2;              // staging row 0..63 (edge in tile)
    const int sc8 = (tid & 3) * 8;        // staging col (8 f32 per lane)

    if (tid < 64) {
        int ii = e0 + tid;
        int e = eid[(ii < NE) ? ii : (NE - 1)];   // pad tail w/ dup edge
        ssrc[tid] = esrc[e];
        sdst[tid] = edst[e];
    }
    for (int i = tid; i < (64 * 68) / 8; i += 256)
        ((uint4*)sL)[i] = make_uint4(0, 0, 0, 0);
    __syncthreads();                      // sdst visible, sL zeroed

    // rank computation (wave 0): run-boundary ballot over sorted dst
    if (tid < 64) {
        int d = sdst[tid];
        bool flag = (tid > 0) && (tid < nT) && (d != sdst[tid - 1]);
        unsigned long long mask = __ballot(flag);
        int rk = (int)__popcll(mask & ((2ull << tid) - 1ull));
        if (tid < nT) {
            rowOfRank[rk] = d;
            sL[rk * 68 + tid] = (u16)0x3F80;      // bf16 1.0
        }
        if (tid == 0) misc[0] = (int)__popcll(mask) + 1;
    }

    f32x4 zero = {0.f, 0.f, 0.f, 0.f};
    f32x4 acc[4][4];
    #pragma unroll
    for (int i = 0; i < 4; ++i)
        #pragma unroll
        for (int j = 0; j < 4; ++j) acc[i][j] = zero;

    // ---- GEMM1: K = 512 (concat mesh_x[src] | grid_x[dst]) ----
    for (int kt = 0; kt < 16; ++kt) {
        const int kg = kt * 32;
        if (kt) __syncthreads();
        {
            const int col = kg + sc8;
            const float* p = (col < DD)
                ? (mesh_x + (size_t)ssrc[sr] * DD + col)
                : (grid_x + (size_t)sdst[sr] * DD + (col - DD));
            float4 v0 = *(const float4*)p;
            float4 v1 = *(const float4*)(p + 4);
            *(uint4*)&aC[sr * 32 + sc8] = pack8(v0, v1);
        }
        #pragma unroll
        for (int i = 0; i < 4; ++i) {
            int flat = tid + 256 * i;
            int n = flat >> 2;
            int c = (flat & 3) * 8;
            *(uint4*)&bC[n * 32 + c] = *(const uint4*)(w1T + (size_t)n * 512 + kg + c);
        }
        __syncthreads();
        bf16x8 af[4], bfr[4];
        #pragma unroll
        for (int et = 0; et < 4; ++et)
            af[et] = *(const bf16x8*)&aC[(et * 16 + m) * 32 + q * 8];
        #pragma unroll
        for (int ht = 0; ht < 4; ++ht)
            bfr[ht] = *(const bf16x8*)&bC[(wv * 64 + ht * 16 + m) * 32 + q * 8];
        #pragma unroll
        for (int ht = 0; ht < 4; ++ht)
            #pragma unroll
            for (int et = 0; et < 4; ++et)
                acc[ht][et] = __builtin_amdgcn_mfma_f32_16x16x32_bf16(
                    bfr[ht], af[et], acc[ht][et], 0, 0, 0);
    }

    // ---- epilogue 1: bias + relu -> hL (h1 [edge][272] bf16) ----
    #pragma unroll
    for (int ht = 0; ht < 4; ++ht) {
        const int hb = wv * 64 + ht * 16 + q * 4;
        const float4 bb = *(const float4*)(b1 + hb);
        #pragma unroll
        for (int et = 0; et < 4; ++et) {
            const int e = et * 16 + m;
            ushort4 o;
            o.x = f2bf(fmaxf(acc[ht][et][0] + bb.x, 0.f));
            o.y = f2bf(fmaxf(acc[ht][et][1] + bb.y, 0.f));
            o.z = f2bf(fmaxf(acc[ht][et][2] + bb.z, 0.f));
            o.w = f2bf(fmaxf(acc[ht][et][3] + bb.w, 0.f));
            *(ushort4*)&hL[e * 272 + hb] = o;
        }
    }
    #pragma unroll
    for (int i = 0; i < 4; ++i)
        #pragma unroll
        for (int j = 0; j < 4; ++j) acc[i][j] = zero;
    __syncthreads();                      // hL visible to all waves

    // ---- GEMM2: K = 256, D2[h][el] into acc ----
    for (int kt = 0; kt < 8; ++kt) {
        const int kg = kt * 32;
        if (kt) __syncthreads();
        #pragma unroll
        for (int i = 0; i < 4; ++i) {
            int flat = tid + 256 * i;
            int n = flat >> 2;
            int c = (flat & 3) * 8;
            *(uint4*)&bC[n * 32 + c] = *(const uint4*)(w2T + (size_t)n * 256 + kg + c);
        }
        __syncthreads();
        bf16x8 af[4], bfr[4];
        #pragma unroll
        for (int et = 0; et < 4; ++et)
            af[et] = *(const bf16x8*)&hL[(et * 16 + m) * 272 + kg + q * 8];
        #pragma unroll
        for (int ht = 0; ht < 4; ++ht)
            bfr[ht] = *(const bf16x8*)&bC[(wv * 64 + ht * 16 + m) * 32 + q * 8];
        #pragma unroll
        for (int ht = 0; ht < 4; ++ht)
            #pragma unroll
            for (int et = 0; et < 4; ++et)
                acc[ht][et] = __builtin_amdgcn_mfma_f32_16x16x32_bf16(
                    bfr[ht], af[et], acc[ht][et], 0, 0, 0);
    }

    // ---- GEMM3: agg_part[h][r] = sum_el h2[el][h] * S[el][r], hi/lo exact ----
    f32x4 acc3[4][4];
    #pragma unroll
    for (int i = 0; i < 4; ++i)
        #pragma unroll
        for (int j = 0; j < 4; ++j) acc3[i][j] = zero;

    for (int pass = 0; pass < 2; ++pass) {
        __syncthreads();                  // hL reads of previous phase done
        // write h2 (hi or lo of acc + b2) transposed into hL as [h=256][68]
        #pragma unroll
        for (int nt = 0; nt < 4; ++nt) {
            const int hb = wv * 64 + nt * 16 + q * 4;
            const float4 bb = *(const float4*)(b2 + hb);
            #pragma unroll
            for (int et = 0; et < 4; ++et) {
                const int el = et * 16 + m;
                #pragma unroll
                for (int j = 0; j < 4; ++j) {
                    float x = acc[nt][et][j] +
                              ((j == 0) ? bb.x : (j == 1) ? bb.y : (j == 2) ? bb.z : bb.w);
                    u16 hi = f2bf(x);
                    u16 v = hi;
                    if (pass) {
                        union { unsigned int i; float f; } hf;
                        hf.i = ((unsigned int)hi) << 16;
                        v = f2bf(x - hf.f);
                    }
                    hL[(hb + j) * 68 + el] = v;
                }
            }
        }
        __syncthreads();
        #pragma unroll
        for (int ks = 0; ks < 2; ++ks) {
            bf16x8 hf[4], sf[4];
            #pragma unroll
            for (int ht = 0; ht < 4; ++ht)
                hf[ht] = *(const bf16x8*)&hL[(wv * 64 + ht * 16 + m) * 68 + ks * 32 + q * 8];
            #pragma unroll
            for (int rt = 0; rt < 4; ++rt)
                sf[rt] = *(const bf16x8*)&sL[(rt * 16 + m) * 68 + ks * 32 + q * 8];
            #pragma unroll
            for (int ht = 0; ht < 4; ++ht)
                #pragma unroll
                for (int rt = 0; rt < 4; ++rt)
                    acc3[ht][rt] = __builtin_amdgcn_mfma_f32_16x16x32_bf16(
                        hf[ht], sf[rt], acc3[ht][rt], 0, 0, 0);
        }
    }

    // ---- epilogue 3: store per-rank partial sums ----
    const int nD = misc[0];
    #pragma unroll
    for (int ht = 0; ht < 4; ++ht) {
        const int h0 = wv * 64 + ht * 16 + q * 4;
        #pragma unroll
        for (int rt = 0; rt < 4; ++rt) {
            const int r = rt * 16 + m;
            if (r < nD) {
                float* p = agg + (size_t)rowOfRank[r] * HH + h0;
                if (r == 0 || r == nD - 1) {      // may straddle block boundary
                    unsafeAtomicAdd(p + 0, acc3[ht][rt][0]);
                    unsafeAtomicAdd(p + 1, acc3[ht][rt][1]);
                    unsafeAtomicAdd(p + 2, acc3[ht][rt][2]);
                    unsafeAtomicAdd(p + 3, acc3[ht][rt][3]);
                } else {                          // exclusively owned row
                    float4 o;
                    o.x = acc3[ht][rt][0];
                    o.y = acc3[ht][rt][1];
                    o.z = acc3[ht][rt][2];
                    o.w = acc3[ht][rt][3];
                    *(float4*)p = o;
                }
            }
        }
    }
}

// ---------------- grid MLP + residual (unchanged) ----------------
// agg is f32 [NG][HH] living in d_out; each block reads only the rows it
// later overwrites with the final f32 output (block-local read-then-write).
// NOTE: agg and out alias — no __restrict__ on them.
__global__ __launch_bounds__(256, 2) void grid_mlp(
    const float* __restrict__ grid_x, const float* agg,
    const u16* __restrict__ w1T, const float* __restrict__ b1,
    const u16* __restrict__ w2T, const float* __restrict__ b2,
    float* out)
{
    __shared__ u16 aC[64 * 32];
    __shared__ u16 bC[256 * 32];
    __shared__ u16 hL[64 * 272];

    const int tid = threadIdx.x;
    const int r0 = blockIdx.x * 64;
    const int wv = tid >> 6;
    const int lane = tid & 63;
    const int m = lane & 15;
    const int q = lane >> 4;
    const int sr = tid >> 2;
    const int sc8 = (tid & 3) * 8;
    int srow = r0 + sr; if (srow >= NG) srow = NG - 1;  // clamp stays inside this block's rows

    f32x4 zero = {0.f, 0.f, 0.f, 0.f};
    f32x4 acc[4][4];
    #pragma unroll
    for (int i = 0; i < 4; ++i)
        #pragma unroll
        for (int j = 0; j < 4; ++j) acc[i][j] = zero;

    // ---- GEMM1: K = 512 (concat grid_x | agg), f32 -> bf16 stage
    for (int kt = 0; kt < 16; ++kt) {
        const int kg = kt * 32;
        if (kt) __syncthreads();
        {
            const int col = kg + sc8;
            const float* p = (col < DD)
                ? (grid_x + (size_t)srow * DD + col)
                : (agg + (size_t)srow * HH + (col - DD));
            float4 v0 = *(const float4*)p;
            float4 v1 = *(const float4*)(p + 4);
            *(uint4*)&aC[sr * 32 + sc8] = pack8(v0, v1);
        }
        #pragma unroll
        for (int i = 0; i < 4; ++i) {
            int flat = tid + 256 * i;
            int n = flat >> 2;
            int c = (flat & 3) * 8;
            *(uint4*)&bC[n * 32 + c] = *(const uint4*)(w1T + (size_t)n * 512 + kg + c);
        }
        __syncthreads();
        bf16x8 af[4], bfr[4];
        #pragma unroll
        for (int et = 0; et < 4; ++et)
            af[et] = *(const bf16x8*)&aC[(et * 16 + m) * 32 + q * 8];
        #pragma unroll
        for (int ht = 0; ht < 4; ++ht)
            bfr[ht] = *(const bf16x8*)&bC[(wv * 64 + ht * 16 + m) * 32 + q * 8];
        #pragma unroll
        for (int ht = 0; ht < 4; ++ht)
            #pragma unroll
            for (int et = 0; et < 4; ++et)
                acc[ht][et] = __builtin_amdgcn_mfma_f32_16x16x32_bf16(
                    bfr[ht], af[et], acc[ht][et], 0, 0, 0);
    }

    #pragma unroll
    for (int ht = 0; ht < 4; ++ht) {
        const int hb = wv * 64 + ht * 16 + q * 4;
        const float4 bb = *(const float4*)(b1 + hb);
        #pragma unroll
        for (int et = 0; et < 4; ++et) {
            const int e = et * 16 + m;
            ushort4 o;
            o.x = f2bf(fmaxf(acc[ht][et][0] + bb.x, 0.f));
            o.y = f2bf(fmaxf(acc[ht][et][1] + bb.y, 0.f));
            o.z = f2bf(fmaxf(acc[ht][et][2] + bb.z, 0.f));
            o.w = f2bf(fmaxf(acc[ht][et][3] + bb.w, 0.f));
            *(ushort4*)&hL[e * 272 + hb] = o;
        }
    }
    #pragma unroll
    for (int i = 0; i < 4; ++i)
        #pragma unroll
        for (int j = 0; j < 4; ++j) acc[i][j] = zero;
    __syncthreads();

    // ---- GEMM2: K = 256
    for (int kt = 0; kt < 8; ++kt) {
        const int kg = kt * 32;
        if (kt) __syncthreads();
        #pragma unroll
        for (int i = 0; i < 4; ++i) {
            int flat = tid + 256 * i;
            int n = flat >> 2;
            int c = (flat & 3) * 8;
            *(uint4*)&bC[n * 32 + c] = *(const uint4*)(w2T + (size_t)n * 256 + kg + c);
        }
        __syncthreads();
        bf16x8 af[4], bfr[4];
        #pragma unroll
        for (int et = 0; et < 4; ++et)
            af[et] = *(const bf16x8*)&hL[(et * 16 + m) * 272 + kg + q * 8];
        #pragma unroll
        for (int ht = 0; ht < 4; ++ht)
            bfr[ht] = *(const bf16x8*)&bC[(wv * 64 + ht * 16 + m) * 32 + q * 8];
        #pragma unroll
        for (int ht = 0; ht < 4; ++ht)
            #pragma unroll
            for (int et = 0; et < 4; ++et)
                acc[ht][et] = __builtin_amdgcn_mfma_f32_16x16x32_bf16(
                    bfr[ht], af[et], acc[ht][et], 0, 0, 0);
    }

    // ---- epilogue: + b2 + residual grid_x, store f32 (overwrites agg rows)
    #pragma unroll
    for (int nt = 0; nt < 4; ++nt) {
        const int nb = wv * 64 + nt * 16 + q * 4;
        const float4 bb = *(const float4*)(b2 + nb);
        #pragma unroll
        for (int et = 0; et < 4; ++et) {
            const int r = r0 + et * 16 + m;
            if (r < NG) {
                const float4 g = *(const float4*)(grid_x + (size_t)r * DD + nb);
                float4 o;
                o.x = acc[nt][et][0] + bb.x + g.x;
                o.y = acc[nt][et][1] + bb.y + g.y;
                o.z = acc[nt][et][2] + bb.z + g.z;
                o.w = acc[nt][et][3] + bb.w + g.w;
                *(float4*)(out + (size_t)r * DD + nb) = o;
            }
        }
    }
}

extern "C" void kernel_launch(void* const* d_in, const int* in_sizes, int n_in,
                              void* d_out, int out_size, void* d_ws, size_t ws_size,
                              hipStream_t stream)
{
    const float* mesh_x = (const float*)d_in[0];
    const float* grid_x = (const float*)d_in[1];
    const int* esrc     = (const int*)d_in[2];
    const int* edst     = (const int*)d_in[3];
    const float* w1e    = (const float*)d_in[4];
    const float* b1e    = (const float*)d_in[5];
    const float* w2e    = (const float*)d_in[6];
    const float* b2e    = (const float*)d_in[7];
    const float* w1g    = (const float*)d_in[8];
    const float* b1g    = (const float*)d_in[9];
    const float* w2g    = (const float*)d_in[10];
    const float* b2g    = (const float*)d_in[11];
    float* out = (float*)d_out;

    // d_ws layout: 4 transposed bf16 weights (768 KB) + CSR (2.0 MB)
    u16* w1eT = (u16*)d_ws;
    u16* w2eT = w1eT + 512 * 256;
    u16* w1gT = w2eT + 256 * 256;
    u16* w2gT = w1gT + 512 * 256;
    int* row_start = (int*)(w2gT + 256 * 256);   // [NG+1] (+1 pad for alignment)
    int* cursor    = row_start + NG + 2;         // [NG]
    int* eid       = cursor + NG;                // [NE]

    // agg f32 [NG][HH] lives in d_out; zero it (atomic-target + empty rows)
    hipMemsetAsync(d_out, 0, (size_t)NG * HH * sizeof(float), stream);
    hipMemsetAsync(cursor, 0, (size_t)NG * sizeof(int), stream);

    transpose_f32_to_bf16T<<<32, 256, 0, stream>>>(w1e, w1eT, 512, 256);
    transpose_f32_to_bf16T<<<16, 256, 0, stream>>>(w2e, w2eT, 256, 256);
    transpose_f32_to_bf16T<<<32, 256, 0, stream>>>(w1g, w1gT, 512, 256);
    transpose_f32_to_bf16T<<<16, 256, 0, stream>>>(w2g, w2gT, 256, 256);

    // CSR build: hist -> scan -> scatter
    hist_k<<<256, 256, 0, stream>>>(edst, cursor);
    scan_k<<<1, 1024, 0, stream>>>(cursor, row_start, cursor);
    scatter_k<<<256, 256, 0, stream>>>(edst, cursor, eid);

    // edge MLP + GEMM3 aggregation (boundary-only atomics)
    const int smem_bytes = 64 * 32 * 2 + 256 * 32 * 2 + 64 * 272 * 2
                         + 64 * 68 * 2 + (64 + 64 + 64 + 16) * 4;   // 64832 B
    hipFuncSetAttribute(reinterpret_cast<const void*>(edge_mlp_csr),
                        hipFuncAttributeMaxDynamicSharedMemorySize, smem_bytes);
    edge_mlp_csr<<<(NE + 63) / 64, 256, smem_bytes, stream>>>(
        mesh_x, grid_x, esrc, edst, eid,
        w1eT, b1e, w2eT, b2e, (float*)d_out);

    grid_mlp<<<(NG + 63) / 64, 256, 0, stream>>>(
        grid_x, (const float*)d_out, w1gT, b1g, w2gT, b2g, out);
}